// Round 10
// baseline (1194.352 us; speedup 1.0000x reference)
//
#include <hip/hip_runtime.h>
#include <hip/hip_bf16.h>

#define N_NODES 10000
#define N_EDGES 80000
#define FN 16
#define FE 8
#define HID 25
#define C1 32
#define C2 64
#define HROW 32   // padded h row (25 used)
#define SLOTS 48  // max out-degree capacity; Poisson(8) => P(deg>=48) ~ 1e-20
#define GRID 512  // 2 blocks/CU x 256 CUs -> co-residency guaranteed (launch_bounds 256,2)
#define GSZ (GRID * 256)

__device__ __forceinline__ float elu_f(float x) { return x > 0.f ? x : (expf(x) - 1.f); }

struct Params {
    const float* x; const int* ei; const float* ea;
    const float* w1a; const float* b1a; const float* w2a; const float* b2a;
    const float* roota; const float* biasa; const float* g1; const float* be1;
    const float* w1b; const float* b1b; const float* w2b; const float* b2b;
    const float* rootb; const float* biasb; const float* g2; const float* be2;
    const float* fc1w; const float* fc1b; const float* fc2w; const float* fc2b;
    float* out;
    int* bar_cnt; int* bar_gen;
    int* cnt_src; int* cnt_dst; float* agg1; float* agg2;
    float* s11; float* s12; float* s21; float* s22;
    int* ebuf; float* h1r; float* h2r; float* P1; float* P2;
    float* a1; float* h1; float* a2; float* partial;
    int zero_words;
};

// Software grid barrier: sense-reversing counter+generation, device scope.
// Safe because GRID (512) <= guaranteed co-resident blocks (2/CU x 256 CU).
__device__ __forceinline__ void gbar(int* cnt, int* gen) {
    __syncthreads();
    if (threadIdx.x == 0) {
        __threadfence();  // release: make this block's writes visible device-wide
        int g = __hip_atomic_load(gen, __ATOMIC_ACQUIRE, __HIP_MEMORY_SCOPE_AGENT);
        int old = __hip_atomic_fetch_add(cnt, 1, __ATOMIC_ACQ_REL, __HIP_MEMORY_SCOPE_AGENT);
        if (old == GRID - 1) {
            __hip_atomic_store(cnt, 0, __ATOMIC_RELAXED, __HIP_MEMORY_SCOPE_AGENT);
            __hip_atomic_fetch_add(gen, 1, __ATOMIC_RELEASE, __HIP_MEMORY_SCOPE_AGENT);
        } else {
            while (__hip_atomic_load(gen, __ATOMIC_ACQUIRE, __HIP_MEMORY_SCOPE_AGENT) == g) {
                __builtin_amdgcn_s_sleep(1);
            }
        }
        __threadfence();  // acquire: don't let later reads see pre-barrier state
    }
    __syncthreads();
}

// m-major precompute: P[n, k*COUT+o] = sum_i x[n,i]*w2[k,i,o]; row k==HID = b2 term.
template <int CIN, int COUT>
__device__ __forceinline__ void pre_phase(const float* __restrict__ xin,
                                          const float* __restrict__ w2,
                                          const float* __restrict__ b2,
                                          float* __restrict__ P, int bid, int tid) {
    constexpr int M = (HID + 1) * COUT;
    constexpr int MB = (M + 255) / 256;
    constexpr int TN = 50;
    constexpr int NG = N_NODES / TN;
    for (int u = bid; u < MB * NG; u += GRID) {
        int mb = u % MB;
        int n0 = (u / MB) * TN;
        int m = mb * 256 + tid;
        if (m >= M) continue;
        int k = m / COUT, o = m % COUT;
        float wreg[CIN];
        if (k < HID) {
#pragma unroll
            for (int i = 0; i < CIN; i++) wreg[i] = w2[(size_t)(k * CIN + i) * COUT + o];
        } else {
#pragma unroll
            for (int i = 0; i < CIN; i++) wreg[i] = b2[i * COUT + o];
        }
        for (int n = n0; n < n0 + TN; n++) {
            const float* xr = xin + (size_t)n * CIN;  // wave-uniform -> s_load
            float s = 0.f;
#pragma unroll
            for (int i = 0; i < CIN; i++) s += xr[i] * wreg[i];
            P[(size_t)n * M + m] = s;
        }
    }
}

// node update + BN partial sums (channel-invariant: GSZ % COUT == 0)
template <int CIN, int COUT>
__device__ __forceinline__ void nodeup_phase(const float* __restrict__ xin,
                                             const float* __restrict__ root,
                                             const float* __restrict__ bias,
                                             const float* __restrict__ agg,
                                             const int* __restrict__ degi,
                                             float* __restrict__ act,
                                             float* s1g, float* s2g,
                                             int bid, int tid, float* red1, float* red2) {
    int o = tid % COUT;
    float b = bias[o];
    float rcol[CIN];
#pragma unroll
    for (int i = 0; i < CIN; i++) rcol[i] = root[i * COUT + o];
    float acc1 = 0.f, acc2 = 0.f;
    for (int t = bid * 256 + tid; t < N_NODES * COUT; t += GSZ) {
        int n = t / COUT;
        const float* xr = xin + (size_t)n * CIN;
        float s = b;
#pragma unroll
        for (int i = 0; i < CIN; i++) s += xr[i] * rcol[i];
        s += agg[t] / fmaxf((float)degi[n], 1.0f);
        float a = elu_f(s);
        act[t] = a;
        acc1 += a; acc2 += a * a;
    }
    red1[tid] = acc1; red2[tid] = acc2;
    __syncthreads();
    for (int s = 128; s >= COUT; s >>= 1) {
        if (tid < s) { red1[tid] += red1[tid + s]; red2[tid] += red2[tid + s]; }
        __syncthreads();
    }
    if (tid < COUT) { atomicAdd(&s1g[tid], red1[tid]); atomicAdd(&s2g[tid], red2[tid]); }
}

__global__ void __launch_bounds__(256, 2) k_mega(Params p) {
    int tid = threadIdx.x;
    int bid = blockIdx.x;
    int gtid = bid * 256 + tid;
    int lane = tid & 63;
    int wv4 = bid * 4 + (tid >> 6);  // global wave id (4 waves/block)

    __shared__ float sw1a[FE * HID], sw1b[FE * HID], sb1a[HID], sb1b[HID];
    __shared__ float red1[256], red2[256];
    for (int i = tid; i < FE * HID; i += 256) { sw1a[i] = p.w1a[i]; sw1b[i] = p.w1b[i]; }
    if (tid < HID) { sb1a[tid] = p.b1a[tid]; sb1b[tid] = p.b1b[tid]; }

    // ---- P0: zero cnt_src..s22 region ----
    int* zbase = (int*)p.cnt_src;
    for (int i = gtid; i < p.zero_words; i += GSZ) zbase[i] = 0;
    gbar(p.bar_cnt, p.bar_gen);

    // ---- P1: bucket-scatter edges + edge-MLP hidden (both convs) + dst degree ----
    for (int e = gtid; e < N_EDGES; e += GSZ) {
        float a[FE];
#pragma unroll
        for (int i = 0; i < FE; i++) a[i] = p.ea[e * FE + i];
        int src = p.ei[e], dst = p.ei[N_EDGES + e];
        int slot = atomicAdd(&p.cnt_src[src], 1);
        int pos = src * SLOTS + slot;
        p.ebuf[pos] = dst;
        atomicAdd(&p.cnt_dst[dst], 1);
        float* h1p = p.h1r + (size_t)pos * HROW;
        float* h2p = p.h2r + (size_t)pos * HROW;
#pragma unroll
        for (int k = 0; k < HID; k++) {
            float s1 = sb1a[k], s2 = sb1b[k];
#pragma unroll
            for (int i = 0; i < FE; i++) { s1 += a[i] * sw1a[i * HID + k]; s2 += a[i] * sw1b[i * HID + k]; }
            h1p[k] = fmaxf(s1, 0.f);
            h2p[k] = fmaxf(s2, 0.f);
        }
    }
    gbar(p.bar_cnt, p.bar_gen);

    // ---- P2: precompute P1 ----
    pre_phase<FN, C1>(p.x, p.w2a, p.b2a, p.P1, bid, tid);
    gbar(p.bar_cnt, p.bar_gen);

    // ---- P3: conv1 message (wave per node, paired edges in half-waves) ----
    {
        constexpr int M = (HID + 1) * C1;
        int o = lane & 31;
        for (int n0 = wv4; n0 < N_NODES; n0 += GRID * 4) {
            int n = __builtin_amdgcn_readfirstlane(n0);
            const float* Pr = p.P1 + (size_t)n * M;
            float Pk[HID + 1];
#pragma unroll
            for (int k = 0; k <= HID; k++) Pk[k] = Pr[k * C1 + o];
            int beg = n * SLOTS, end = beg + p.cnt_src[n];
            int idx = beg;
            for (; idx + 1 < end; idx += 2) {
                int d0 = p.ebuf[idx], d1 = p.ebuf[idx + 1];
                const float* h0 = p.h1r + (size_t)idx * HROW;
                const float* h1 = p.h1r + (size_t)(idx + 1) * HROW;
                float s0 = Pk[HID], s1 = Pk[HID];
#pragma unroll
                for (int k = 0; k < HID; k++) { s0 += h0[k] * Pk[k]; s1 += h1[k] * Pk[k]; }
                float val = (lane < 32) ? s0 : s1;
                int dsel = (lane < 32) ? d0 : d1;
                atomicAdd(&p.agg1[dsel * C1 + o], val);
            }
            if (idx < end) {
                int d0 = p.ebuf[idx];
                const float* h0 = p.h1r + (size_t)idx * HROW;
                float s0 = Pk[HID];
#pragma unroll
                for (int k = 0; k < HID; k++) s0 += h0[k] * Pk[k];
                if (lane < 32) atomicAdd(&p.agg1[d0 * C1 + o], s0);
            }
        }
    }
    gbar(p.bar_cnt, p.bar_gen);

    // ---- P4: node update 1 (+BN1 sums) ----
    nodeup_phase<FN, C1>(p.x, p.roota, p.biasa, p.agg1, p.cnt_dst, p.a1,
                         p.s11, p.s12, bid, tid, red1, red2);
    gbar(p.bar_cnt, p.bar_gen);

    // ---- P5: BN1 + elu -> h1 ----
    for (int t = gtid; t < N_NODES * C1; t += GSZ) {
        int o = t % C1;
        float m = p.s11[o] * (1.0f / N_NODES);
        float v = p.s12[o] * (1.0f / N_NODES) - m * m;
        float xv = (p.a1[t] - m) * rsqrtf(v + 1e-5f) * p.g1[o] + p.be1[o];
        p.h1[t] = elu_f(xv);
    }
    gbar(p.bar_cnt, p.bar_gen);

    // ---- P6: precompute P2 ----
    pre_phase<C1, C2>(p.h1, p.w2b, p.b2b, p.P2, bid, tid);
    gbar(p.bar_cnt, p.bar_gen);

    // ---- P7: conv2 message (wave per node, lane = channel, 2-edge unroll) ----
    {
        constexpr int M = (HID + 1) * C2;
        for (int n0 = wv4; n0 < N_NODES; n0 += GRID * 4) {
            int n = __builtin_amdgcn_readfirstlane(n0);
            const float* Pr = p.P2 + (size_t)n * M;
            float Pk[HID + 1];
#pragma unroll
            for (int k = 0; k <= HID; k++) Pk[k] = Pr[k * C2 + lane];
            int beg = n * SLOTS, end = beg + p.cnt_src[n];
            int idx = beg;
            for (; idx + 1 < end; idx += 2) {
                int d0 = p.ebuf[idx], d1 = p.ebuf[idx + 1];
                const float* h0 = p.h2r + (size_t)idx * HROW;
                const float* h1 = p.h2r + (size_t)(idx + 1) * HROW;
                float s0 = Pk[HID], s1 = Pk[HID];
#pragma unroll
                for (int k = 0; k < HID; k++) { s0 += h0[k] * Pk[k]; s1 += h1[k] * Pk[k]; }
                atomicAdd(&p.agg2[d0 * C2 + lane], s0);
                atomicAdd(&p.agg2[d1 * C2 + lane], s1);
            }
            if (idx < end) {
                int d0 = p.ebuf[idx];
                const float* h0 = p.h2r + (size_t)idx * HROW;
                float s0 = Pk[HID];
#pragma unroll
                for (int k = 0; k < HID; k++) s0 += h0[k] * Pk[k];
                atomicAdd(&p.agg2[d0 * C2 + lane], s0);
            }
        }
    }
    gbar(p.bar_cnt, p.bar_gen);

    // ---- P8: node update 2 (+BN2 sums) ----
    nodeup_phase<C1, C2>(p.h1, p.rootb, p.biasb, p.agg2, p.cnt_dst, p.a2,
                         p.s21, p.s22, bid, tid, red1, red2);
    gbar(p.bar_cnt, p.bar_gen);

    // ---- P9: BN2+elu fused fc1+elu+fc2+elu -> per-block partial ----
    {
        int wave = tid >> 6;
        float m = p.s21[lane] * (1.0f / N_NODES);
        float var = p.s22[lane] * (1.0f / N_NODES) - m * m;
        float scale = rsqrtf(var + 1e-5f) * p.g2[lane];
        float shift = p.be2[lane] - m * scale;
        float b0 = p.fc1b[lane], b1 = p.fc1b[lane + 64];
        float w0 = p.fc2w[lane], w1 = p.fc2w[lane + 64];
        float fb = p.fc2b[0];
        float acc = 0.f;
        for (int n = wv4; n < N_NODES; n += GRID * 4) {
            float hval = elu_f(p.a2[(size_t)n * C2 + lane] * scale + shift);
            float s0 = b0, s1 = b1;
#pragma unroll
            for (int i = 0; i < C2; i++) {
                float hv = __shfl(hval, i);
                s0 += hv * p.fc1w[i * 128 + lane];
                s1 += hv * p.fc1w[i * 128 + 64 + lane];
            }
            float v = elu_f(s0) * w0 + elu_f(s1) * w1;
#pragma unroll
            for (int off2 = 32; off2 > 0; off2 >>= 1) v += __shfl_down(v, off2);
            if (lane == 0) acc += elu_f(v + fb);
        }
        __syncthreads();  // red1 reuse
        if (lane == 0) red1[wave] = acc;
        __syncthreads();
        if (tid == 0) p.partial[bid] = red1[0] + red1[1] + red1[2] + red1[3];
    }
    gbar(p.bar_cnt, p.bar_gen);

    // ---- P10: block 0 reduces partials -> out ----
    if (bid == 0) {
        float s = 0.f;
        for (int i = tid; i < GRID; i += 256) s += p.partial[i];
        red1[tid] = s;
        __syncthreads();
        for (int k = 128; k > 0; k >>= 1) {
            if (tid < k) red1[tid] += red1[tid + k];
            __syncthreads();
        }
        if (tid == 0) *p.out = red1[0];
    }
}

extern "C" void kernel_launch(void* const* d_in, const int* in_sizes, int n_in,
                              void* d_out, int out_size, void* d_ws, size_t ws_size,
                              hipStream_t stream) {
    Params p;
    p.x     = (const float*)d_in[0];
    p.ei    = (const int*)d_in[1];
    p.ea    = (const float*)d_in[2];
    p.w1a   = (const float*)d_in[3];
    p.b1a   = (const float*)d_in[4];
    p.w2a   = (const float*)d_in[5];
    p.b2a   = (const float*)d_in[6];
    p.roota = (const float*)d_in[7];
    p.biasa = (const float*)d_in[8];
    p.g1    = (const float*)d_in[9];
    p.be1   = (const float*)d_in[10];
    p.w1b   = (const float*)d_in[11];
    p.b1b   = (const float*)d_in[12];
    p.w2b   = (const float*)d_in[13];
    p.b2b   = (const float*)d_in[14];
    p.rootb = (const float*)d_in[15];
    p.biasb = (const float*)d_in[16];
    p.g2    = (const float*)d_in[17];
    p.be2   = (const float*)d_in[18];
    p.fc1w  = (const float*)d_in[19];
    p.fc1b  = (const float*)d_in[20];
    p.fc2w  = (const float*)d_in[21];
    p.fc2b  = (const float*)d_in[22];
    p.out   = (float*)d_out;

    char* ws = (char*)d_ws;
    size_t off = 0;
    auto alloc = [&](size_t nelem) -> void* {
        void* q = (void*)(ws + off);
        off += nelem * 4;
        off = (off + 255) & ~(size_t)255;
        return q;
    };
    // barrier words first (zeroed by tiny memsetAsync below)
    p.bar_cnt = (int*)alloc(1);
    p.bar_gen = (int*)alloc(1);
    size_t bar_bytes = off;  // 256-aligned
    // region zeroed by kernel phase 0 (cnt_src..s22)
    size_t zstart = off;
    p.cnt_src = (int*)alloc(N_NODES);
    p.cnt_dst = (int*)alloc(N_NODES);
    p.agg1    = (float*)alloc((size_t)N_NODES * C1);
    p.agg2    = (float*)alloc((size_t)N_NODES * C2);
    p.s11     = (float*)alloc(C1);
    p.s12     = (float*)alloc(C1);
    p.s21     = (float*)alloc(C2);
    p.s22     = (float*)alloc(C2);
    p.zero_words = (int)((off - zstart) / 4);
    p.ebuf    = (int*)alloc((size_t)N_NODES * SLOTS);
    p.h1r     = (float*)alloc((size_t)N_NODES * SLOTS * HROW);
    p.h2r     = (float*)alloc((size_t)N_NODES * SLOTS * HROW);
    p.P1      = (float*)alloc((size_t)N_NODES * (HID + 1) * C1);
    p.P2      = (float*)alloc((size_t)N_NODES * (HID + 1) * C2);
    p.a1      = (float*)alloc((size_t)N_NODES * C1);
    p.h1      = (float*)alloc((size_t)N_NODES * C1);
    p.a2      = (float*)alloc((size_t)N_NODES * C2);
    p.partial = (float*)alloc(GRID);
    (void)ws_size;
    (void)in_sizes; (void)n_in; (void)out_size;

    hipMemsetAsync(d_ws, 0, bar_bytes, stream);  // zero barrier counter+generation
    k_mega<<<dim3(GRID), dim3(256), 0, stream>>>(p);
}

// Round 11
// 543.426 us; speedup vs baseline: 2.1978x; 2.1978x over previous
//
#include <hip/hip_runtime.h>
#include <hip/hip_bf16.h>

#define N_NODES 10000
#define N_EDGES 80000
#define FN 16
#define FE 8
#define HID 25
#define C1 32
#define C2 64
#define HROW 32   // padded h row (25 used)
#define SLOTS 48  // max out-degree capacity; Poisson(8) => P(deg>=48) ~ 1e-20
#define GRID 256  // 1 block/CU x 256 CUs; block=1024 -> 16 waves/CU resident
#define BLK 1024
#define GSZ (GRID * BLK)
#define NWAVE (GRID * (BLK / 64))

__device__ __forceinline__ float elu_f(float x) { return x > 0.f ? x : (expf(x) - 1.f); }

struct Params {
    const float* x; const int* ei; const float* ea;
    const float* w1a; const float* b1a; const float* w2a; const float* b2a;
    const float* roota; const float* biasa; const float* g1; const float* be1;
    const float* w1b; const float* b1b; const float* w2b; const float* b2b;
    const float* rootb; const float* biasb; const float* g2; const float* be2;
    const float* fc1w; const float* fc1b; const float* fc2w; const float* fc2b;
    float* out;
    int* bar_cnt; int* bar_gen;
    int* cnt_src; int* cnt_dst; float* agg1; float* agg2;
    float* s11; float* s12; float* s21; float* s22;
    int* ebuf; float* h1r; float* h2r; float* P1; float* P2;
    float* a1; float* h1; float* a2;
};

// Software grid barrier. Spin uses RELAXED agent loads (no cache maintenance
// per poll); exactly one release fence (L2 writeback) on entry and one acquire
// fence (L2 inv) on exit per block. Safe: GRID (256) == 1 block/CU co-resident.
__device__ __forceinline__ void gbar(int* cnt, int* gen) {
    __syncthreads();
    if (threadIdx.x == 0) {
        __builtin_amdgcn_fence(__ATOMIC_RELEASE, "agent");  // wb dirty L2 once
        int g = __hip_atomic_load(gen, __ATOMIC_RELAXED, __HIP_MEMORY_SCOPE_AGENT);
        int old = __hip_atomic_fetch_add(cnt, 1, __ATOMIC_RELAXED, __HIP_MEMORY_SCOPE_AGENT);
        if (old == GRID - 1) {
            __hip_atomic_store(cnt, 0, __ATOMIC_RELAXED, __HIP_MEMORY_SCOPE_AGENT);
            // RELEASE orders the cnt reset before gen becomes visible
            __hip_atomic_fetch_add(gen, 1, __ATOMIC_RELEASE, __HIP_MEMORY_SCOPE_AGENT);
        } else {
            while (__hip_atomic_load(gen, __ATOMIC_RELAXED, __HIP_MEMORY_SCOPE_AGENT) == g)
                __builtin_amdgcn_s_sleep(8);
        }
        __builtin_amdgcn_fence(__ATOMIC_ACQUIRE, "agent");  // inv L2 once
    }
    __syncthreads();
}

// m-major precompute: P[n, k*COUT+o] = sum_i x[n,i]*w2[k,i,o]; row k==HID = b2 term.
template <int CIN, int COUT>
__device__ __forceinline__ void pre_phase(const float* __restrict__ xin,
                                          const float* __restrict__ w2,
                                          const float* __restrict__ b2,
                                          float* __restrict__ P, int bid, int tid) {
    constexpr int M = (HID + 1) * COUT;
    constexpr int MB = (M + BLK - 1) / BLK;
    constexpr int TN = 50;
    constexpr int NG = N_NODES / TN;
    for (int u = bid; u < MB * NG; u += GRID) {
        int mb = u % MB;
        int n0 = (u / MB) * TN;
        int m = mb * BLK + tid;
        if (m >= M) continue;
        int k = m / COUT, o = m % COUT;
        float wreg[CIN];
        if (k < HID) {
#pragma unroll
            for (int i = 0; i < CIN; i++) wreg[i] = w2[(size_t)(k * CIN + i) * COUT + o];
        } else {
#pragma unroll
            for (int i = 0; i < CIN; i++) wreg[i] = b2[i * COUT + o];
        }
        for (int n = n0; n < n0 + TN; n++) {
            const float* xr = xin + (size_t)n * CIN;  // wave-uniform -> s_load
            float s = 0.f;
#pragma unroll
            for (int i = 0; i < CIN; i++) s += xr[i] * wreg[i];
            P[(size_t)n * M + m] = s;
        }
    }
}

// node update + BN partial sums (channel-invariant: GSZ % COUT == 0)
template <int CIN, int COUT>
__device__ __forceinline__ void nodeup_phase(const float* __restrict__ xin,
                                             const float* __restrict__ root,
                                             const float* __restrict__ bias,
                                             const float* __restrict__ agg,
                                             const int* __restrict__ degi,
                                             float* __restrict__ act,
                                             float* s1g, float* s2g,
                                             int bid, int tid, float* red1, float* red2) {
    int o = tid % COUT;
    float b = bias[o];
    float rcol[CIN];
#pragma unroll
    for (int i = 0; i < CIN; i++) rcol[i] = root[i * COUT + o];
    float acc1 = 0.f, acc2 = 0.f;
    for (int t = bid * BLK + tid; t < N_NODES * COUT; t += GSZ) {
        int n = t / COUT;
        const float* xr = xin + (size_t)n * CIN;
        float s = b;
#pragma unroll
        for (int i = 0; i < CIN; i++) s += xr[i] * rcol[i];
        s += agg[t] / fmaxf((float)degi[n], 1.0f);
        float a = elu_f(s);
        act[t] = a;
        acc1 += a; acc2 += a * a;
    }
    red1[tid] = acc1; red2[tid] = acc2;
    __syncthreads();
    for (int s = BLK / 2; s >= COUT; s >>= 1) {
        if (tid < s) { red1[tid] += red1[tid + s]; red2[tid] += red2[tid + s]; }
        __syncthreads();
    }
    if (tid < COUT) { atomicAdd(&s1g[tid], red1[tid]); atomicAdd(&s2g[tid], red2[tid]); }
}

__global__ void __launch_bounds__(BLK, 4) k_mega(Params p) {
    int tid = threadIdx.x;
    int bid = blockIdx.x;
    int gtid = bid * BLK + tid;
    int lane = tid & 63;
    int wvid = bid * (BLK / 64) + (tid >> 6);  // global wave id

    __shared__ float sw1a[FE * HID], sw1b[FE * HID], sb1a[HID], sb1b[HID];
    __shared__ float red1[BLK], red2[BLK];
    for (int i = tid; i < FE * HID; i += BLK) { sw1a[i] = p.w1a[i]; sw1b[i] = p.w1b[i]; }
    if (tid < HID) { sb1a[tid] = p.b1a[tid]; sb1b[tid] = p.b1b[tid]; }
    __syncthreads();

    // ---- Phase A: bucket-scatter edges + edge-MLP hidden (both convs) + dst
    //      degree; then (independent producer) precompute P1. Zero region is
    //      cleared by hipMemsetAsync before launch. ----
    for (int e = gtid; e < N_EDGES; e += GSZ) {
        float a[FE];
#pragma unroll
        for (int i = 0; i < FE; i++) a[i] = p.ea[e * FE + i];
        int src = p.ei[e], dst = p.ei[N_EDGES + e];
        int slot = atomicAdd(&p.cnt_src[src], 1);
        int pos = src * SLOTS + slot;
        p.ebuf[pos] = dst;
        atomicAdd(&p.cnt_dst[dst], 1);
        float* h1p = p.h1r + (size_t)pos * HROW;
        float* h2p = p.h2r + (size_t)pos * HROW;
#pragma unroll
        for (int k = 0; k < HID; k++) {
            float s1 = sb1a[k], s2 = sb1b[k];
#pragma unroll
            for (int i = 0; i < FE; i++) { s1 += a[i] * sw1a[i * HID + k]; s2 += a[i] * sw1b[i * HID + k]; }
            h1p[k] = fmaxf(s1, 0.f);
            h2p[k] = fmaxf(s2, 0.f);
        }
    }
    pre_phase<FN, C1>(p.x, p.w2a, p.b2a, p.P1, bid, tid);
    gbar(p.bar_cnt, p.bar_gen);

    // ---- Phase B: conv1 message (wave per node, paired edges in half-waves) ----
    {
        constexpr int M = (HID + 1) * C1;
        int o = lane & 31;
        for (int n0 = wvid; n0 < N_NODES; n0 += NWAVE) {
            int n = __builtin_amdgcn_readfirstlane(n0);
            const float* Pr = p.P1 + (size_t)n * M;
            float Pk[HID + 1];
#pragma unroll
            for (int k = 0; k <= HID; k++) Pk[k] = Pr[k * C1 + o];
            int beg = n * SLOTS, end = beg + p.cnt_src[n];
            int idx = beg;
            for (; idx + 1 < end; idx += 2) {
                int d0 = p.ebuf[idx], d1 = p.ebuf[idx + 1];
                const float* h0 = p.h1r + (size_t)idx * HROW;
                const float* h1 = p.h1r + (size_t)(idx + 1) * HROW;
                float s0 = Pk[HID], s1 = Pk[HID];
#pragma unroll
                for (int k = 0; k < HID; k++) { s0 += h0[k] * Pk[k]; s1 += h1[k] * Pk[k]; }
                float val = (lane < 32) ? s0 : s1;
                int dsel = (lane < 32) ? d0 : d1;
                atomicAdd(&p.agg1[dsel * C1 + o], val);
            }
            if (idx < end) {
                int d0 = p.ebuf[idx];
                const float* h0 = p.h1r + (size_t)idx * HROW;
                float s0 = Pk[HID];
#pragma unroll
                for (int k = 0; k < HID; k++) s0 += h0[k] * Pk[k];
                if (lane < 32) atomicAdd(&p.agg1[d0 * C1 + o], s0);
            }
        }
    }
    gbar(p.bar_cnt, p.bar_gen);

    // ---- Phase C: node update 1 (+BN1 sums) ----
    nodeup_phase<FN, C1>(p.x, p.roota, p.biasa, p.agg1, p.cnt_dst, p.a1,
                         p.s11, p.s12, bid, tid, red1, red2);
    gbar(p.bar_cnt, p.bar_gen);

    // ---- Phase D: BN1 + elu -> h1 ----
    for (int t = gtid; t < N_NODES * C1; t += GSZ) {
        int o = t % C1;
        float m = p.s11[o] * (1.0f / N_NODES);
        float v = p.s12[o] * (1.0f / N_NODES) - m * m;
        float xv = (p.a1[t] - m) * rsqrtf(v + 1e-5f) * p.g1[o] + p.be1[o];
        p.h1[t] = elu_f(xv);
    }
    gbar(p.bar_cnt, p.bar_gen);

    // ---- Phase E: precompute P2 ----
    pre_phase<C1, C2>(p.h1, p.w2b, p.b2b, p.P2, bid, tid);
    gbar(p.bar_cnt, p.bar_gen);

    // ---- Phase F: conv2 message (wave per node, lane = channel, 2-edge unroll) ----
    {
        constexpr int M = (HID + 1) * C2;
        for (int n0 = wvid; n0 < N_NODES; n0 += NWAVE) {
            int n = __builtin_amdgcn_readfirstlane(n0);
            const float* Pr = p.P2 + (size_t)n * M;
            float Pk[HID + 1];
#pragma unroll
            for (int k = 0; k <= HID; k++) Pk[k] = Pr[k * C2 + lane];
            int beg = n * SLOTS, end = beg + p.cnt_src[n];
            int idx = beg;
            for (; idx + 1 < end; idx += 2) {
                int d0 = p.ebuf[idx], d1 = p.ebuf[idx + 1];
                const float* h0 = p.h2r + (size_t)idx * HROW;
                const float* h1 = p.h2r + (size_t)(idx + 1) * HROW;
                float s0 = Pk[HID], s1 = Pk[HID];
#pragma unroll
                for (int k = 0; k < HID; k++) { s0 += h0[k] * Pk[k]; s1 += h1[k] * Pk[k]; }
                atomicAdd(&p.agg2[d0 * C2 + lane], s0);
                atomicAdd(&p.agg2[d1 * C2 + lane], s1);
            }
            if (idx < end) {
                int d0 = p.ebuf[idx];
                const float* h0 = p.h2r + (size_t)idx * HROW;
                float s0 = Pk[HID];
#pragma unroll
                for (int k = 0; k < HID; k++) s0 += h0[k] * Pk[k];
                atomicAdd(&p.agg2[d0 * C2 + lane], s0);
            }
        }
    }
    gbar(p.bar_cnt, p.bar_gen);

    // ---- Phase G: node update 2 (+BN2 sums); block 0 zeroes out[0] ----
    if (bid == 0 && tid == 0) *p.out = 0.f;
    nodeup_phase<C1, C2>(p.h1, p.rootb, p.biasb, p.agg2, p.cnt_dst, p.a2,
                         p.s21, p.s22, bid, tid, red1, red2);
    gbar(p.bar_cnt, p.bar_gen);

    // ---- Phase H: BN2+elu fused fc1+elu+fc2+elu -> one atomicAdd per block ----
    {
        int wave = tid >> 6;
        float m = p.s21[lane] * (1.0f / N_NODES);
        float var = p.s22[lane] * (1.0f / N_NODES) - m * m;
        float scale = rsqrtf(var + 1e-5f) * p.g2[lane];
        float shift = p.be2[lane] - m * scale;
        float b0 = p.fc1b[lane], b1 = p.fc1b[lane + 64];
        float w0 = p.fc2w[lane], w1 = p.fc2w[lane + 64];
        float fb = p.fc2b[0];
        float acc = 0.f;
        for (int n = wvid; n < N_NODES; n += NWAVE) {
            float hval = elu_f(p.a2[(size_t)n * C2 + lane] * scale + shift);
            float s0 = b0, s1 = b1;
#pragma unroll
            for (int i = 0; i < C2; i++) {
                float hv = __shfl(hval, i);
                s0 += hv * p.fc1w[i * 128 + lane];
                s1 += hv * p.fc1w[i * 128 + 64 + lane];
            }
            float v = elu_f(s0) * w0 + elu_f(s1) * w1;
#pragma unroll
            for (int off2 = 32; off2 > 0; off2 >>= 1) v += __shfl_down(v, off2);
            if (lane == 0) acc += elu_f(v + fb);
        }
        if (lane == 0) red1[wave] = acc;
        __syncthreads();
        if (tid == 0) {
            float s = 0.f;
#pragma unroll
            for (int w = 0; w < BLK / 64; w++) s += red1[w];
            atomicAdd(p.out, s);
        }
    }
}

extern "C" void kernel_launch(void* const* d_in, const int* in_sizes, int n_in,
                              void* d_out, int out_size, void* d_ws, size_t ws_size,
                              hipStream_t stream) {
    Params p;
    p.x     = (const float*)d_in[0];
    p.ei    = (const int*)d_in[1];
    p.ea    = (const float*)d_in[2];
    p.w1a   = (const float*)d_in[3];
    p.b1a   = (const float*)d_in[4];
    p.w2a   = (const float*)d_in[5];
    p.b2a   = (const float*)d_in[6];
    p.roota = (const float*)d_in[7];
    p.biasa = (const float*)d_in[8];
    p.g1    = (const float*)d_in[9];
    p.be1   = (const float*)d_in[10];
    p.w1b   = (const float*)d_in[11];
    p.b1b   = (const float*)d_in[12];
    p.w2b   = (const float*)d_in[13];
    p.b2b   = (const float*)d_in[14];
    p.rootb = (const float*)d_in[15];
    p.biasb = (const float*)d_in[16];
    p.g2    = (const float*)d_in[17];
    p.be2   = (const float*)d_in[18];
    p.fc1w  = (const float*)d_in[19];
    p.fc1b  = (const float*)d_in[20];
    p.fc2w  = (const float*)d_in[21];
    p.fc2b  = (const float*)d_in[22];
    p.out   = (float*)d_out;

    char* ws = (char*)d_ws;
    size_t off = 0;
    auto alloc = [&](size_t nelem) -> void* {
        void* q = (void*)(ws + off);
        off += nelem * 4;
        off = (off + 255) & ~(size_t)255;
        return q;
    };
    // region zeroed by one hipMemsetAsync: barrier words + cnt/agg/BN-sum block
    p.bar_cnt = (int*)alloc(1);
    p.bar_gen = (int*)alloc(1);
    p.cnt_src = (int*)alloc(N_NODES);
    p.cnt_dst = (int*)alloc(N_NODES);
    p.agg1    = (float*)alloc((size_t)N_NODES * C1);
    p.agg2    = (float*)alloc((size_t)N_NODES * C2);
    p.s11     = (float*)alloc(C1);
    p.s12     = (float*)alloc(C1);
    p.s21     = (float*)alloc(C2);
    p.s22     = (float*)alloc(C2);
    size_t zero_bytes = off;
    p.ebuf    = (int*)alloc((size_t)N_NODES * SLOTS);
    p.h1r     = (float*)alloc((size_t)N_NODES * SLOTS * HROW);
    p.h2r     = (float*)alloc((size_t)N_NODES * SLOTS * HROW);
    p.P1      = (float*)alloc((size_t)N_NODES * (HID + 1) * C1);
    p.P2      = (float*)alloc((size_t)N_NODES * (HID + 1) * C2);
    p.a1      = (float*)alloc((size_t)N_NODES * C1);
    p.h1      = (float*)alloc((size_t)N_NODES * C1);
    p.a2      = (float*)alloc((size_t)N_NODES * C2);
    (void)ws_size;
    (void)in_sizes; (void)n_in; (void)out_size;

    hipMemsetAsync(d_ws, 0, zero_bytes, stream);
    k_mega<<<dim3(GRID), dim3(BLK), 0, stream>>>(p);
}

// Round 12
// 269.932 us; speedup vs baseline: 4.4246x; 2.0132x over previous
//
#include <hip/hip_runtime.h>
#include <hip/hip_bf16.h>

#define N_NODES 10000
#define N_EDGES 80000
#define FN 16
#define FE 8
#define HID 25
#define C1 32
#define C2 64
#define NU_BLOCKS 256
#define FC_BLOCKS 640
#define HROW 32   // padded h row (25 used)
#define SLOTS 48  // bucket capacity; Poisson(8) => P(deg>=48) ~ 1e-20
#define SC_BLOCKS ((N_EDGES + 255) / 256)  // 313

__device__ __forceinline__ float elu_f(float x) { return x > 0.f ? x : (expf(x) - 1.f); }

// --- K1: two independent jobs split by blockIdx:
//     blocks [0, SC_BLOCKS): bucket-scatter edges + edge-MLP hidden (both convs)
//                            + dst degree histogram
//     blocks [SC_BLOCKS, +PRE1_BLOCKS): m-major precompute of P1 ---
template <int CIN, int COUT>
__device__ __forceinline__ void pre_block(const float* __restrict__ xin,
                                          const float* __restrict__ w2,
                                          const float* __restrict__ b2,
                                          float* __restrict__ P, int u, int tid) {
    constexpr int M = (HID + 1) * COUT;
    constexpr int MB = (M + 255) / 256;
    constexpr int TN = 50;
    int mb = u % MB;
    int n0 = (u / MB) * TN;
    int m = mb * 256 + tid;
    if (m >= M) return;
    int k = m / COUT, o = m % COUT;
    float wreg[CIN];
    if (k < HID) {
#pragma unroll
        for (int i = 0; i < CIN; i++) wreg[i] = w2[(size_t)(k * CIN + i) * COUT + o];
    } else {
#pragma unroll
        for (int i = 0; i < CIN; i++) wreg[i] = b2[i * COUT + o];
    }
    for (int n = n0; n < n0 + TN; n++) {
        const float* xr = xin + (size_t)n * CIN;  // wave-uniform -> s_load
        float s = 0.f;
#pragma unroll
        for (int i = 0; i < CIN; i++) s += xr[i] * wreg[i];
        P[(size_t)n * M + m] = s;
    }
}

__global__ void k_scatter_pre1(const float* __restrict__ ea, const int* __restrict__ ei,
                               const float* __restrict__ w1a, const float* __restrict__ b1a,
                               const float* __restrict__ w1b, const float* __restrict__ b1b,
                               const float* __restrict__ x, const float* __restrict__ w2a,
                               const float* __restrict__ b2a,
                               int* __restrict__ cnt_src, int* __restrict__ cnt_dst,
                               int* __restrict__ ebuf, float* __restrict__ h1r,
                               float* __restrict__ h2r, float* __restrict__ P1) {
    int tid = threadIdx.x;
    int bid = blockIdx.x;
    if (bid >= SC_BLOCKS) {
        pre_block<FN, C1>(x, w2a, b2a, P1, bid - SC_BLOCKS, tid);
        return;
    }
    __shared__ float sw1a[FE * HID], sw1b[FE * HID], sb1a[HID], sb1b[HID];
    for (int i = tid; i < FE * HID; i += 256) { sw1a[i] = w1a[i]; sw1b[i] = w1b[i]; }
    if (tid < HID) { sb1a[tid] = b1a[tid]; sb1b[tid] = b1b[tid]; }
    __syncthreads();
    int e = bid * 256 + tid;
    if (e >= N_EDGES) return;
    float a[FE];
#pragma unroll
    for (int i = 0; i < FE; i++) a[i] = ea[e * FE + i];
    int src = ei[e], dst = ei[N_EDGES + e];
    int slot = atomicAdd(&cnt_src[src], 1);
    int pos = src * SLOTS + slot;
    ebuf[pos] = dst;
    atomicAdd(&cnt_dst[dst], 1);
    float* h1p = h1r + (size_t)pos * HROW;
    float* h2p = h2r + (size_t)pos * HROW;
#pragma unroll
    for (int k = 0; k < HID; k++) {
        float s1 = sb1a[k], s2 = sb1b[k];
#pragma unroll
        for (int i = 0; i < FE; i++) { s1 += a[i] * sw1a[i * HID + k]; s2 += a[i] * sw1b[i * HID + k]; }
        h1p[k] = fmaxf(s1, 0.f);
        h2p[k] = fmaxf(s2, 0.f);
    }
}

// --- K5: conv2 precompute (standalone) ---
template <int CIN, int COUT>
__global__ void k_precompute(const float* __restrict__ xin, const float* __restrict__ w2,
                             const float* __restrict__ b2, float* __restrict__ P) {
    pre_block<CIN, COUT>(xin, w2, b2, P, blockIdx.x, threadIdx.x);
}

// --- K2: conv1 message. Wave per node; paired edges in half-waves; node index
//         scalarized -> bucket/h-row loads become s_load. ---
__global__ void k_msg_c1(const float* __restrict__ P, const int* __restrict__ cnt_src,
                         const int* __restrict__ ebuf, const float* __restrict__ h1r,
                         float* __restrict__ agg) {
    constexpr int M = (HID + 1) * C1;
    int lane = threadIdx.x & 63;
    int o = lane & 31;
    int n = __builtin_amdgcn_readfirstlane(blockIdx.x * 4 + (threadIdx.x >> 6));
    if (n >= N_NODES) return;
    const float* Pr = P + (size_t)n * M;
    float Pk[HID + 1];
#pragma unroll
    for (int k = 0; k <= HID; k++) Pk[k] = Pr[k * C1 + o];
    int beg = n * SLOTS, end = beg + cnt_src[n];
    int idx = beg;
    for (; idx + 1 < end; idx += 2) {
        int d0 = ebuf[idx], d1 = ebuf[idx + 1];
        const float* h0 = h1r + (size_t)idx * HROW;
        const float* h1 = h1r + (size_t)(idx + 1) * HROW;
        float s0 = Pk[HID], s1 = Pk[HID];
#pragma unroll
        for (int k = 0; k < HID; k++) { s0 += h0[k] * Pk[k]; s1 += h1[k] * Pk[k]; }
        float val = (lane < 32) ? s0 : s1;
        int dsel = (lane < 32) ? d0 : d1;
        atomicAdd(&agg[dsel * C1 + o], val);
    }
    if (idx < end) {
        int d0 = ebuf[idx];
        const float* h0 = h1r + (size_t)idx * HROW;
        float s0 = Pk[HID];
#pragma unroll
        for (int k = 0; k < HID; k++) s0 += h0[k] * Pk[k];
        if (lane < 32) atomicAdd(&agg[d0 * C1 + o], s0);
    }
}

// --- K6: conv2 message. Wave per node; lane = channel; 2-edge unroll. ---
__global__ void k_msg_c2(const float* __restrict__ P, const int* __restrict__ cnt_src,
                         const int* __restrict__ ebuf, const float* __restrict__ h2r,
                         float* __restrict__ agg) {
    constexpr int M = (HID + 1) * C2;
    int lane = threadIdx.x & 63;
    int n = __builtin_amdgcn_readfirstlane(blockIdx.x * 4 + (threadIdx.x >> 6));
    if (n >= N_NODES) return;
    const float* Pr = P + (size_t)n * M;
    float Pk[HID + 1];
#pragma unroll
    for (int k = 0; k <= HID; k++) Pk[k] = Pr[k * C2 + lane];
    int beg = n * SLOTS, end = beg + cnt_src[n];
    int idx = beg;
    for (; idx + 1 < end; idx += 2) {
        int d0 = ebuf[idx], d1 = ebuf[idx + 1];
        const float* h0 = h2r + (size_t)idx * HROW;
        const float* h1 = h2r + (size_t)(idx + 1) * HROW;
        float s0 = Pk[HID], s1 = Pk[HID];
#pragma unroll
        for (int k = 0; k < HID; k++) { s0 += h0[k] * Pk[k]; s1 += h1[k] * Pk[k]; }
        atomicAdd(&agg[d0 * C2 + lane], s0);
        atomicAdd(&agg[d1 * C2 + lane], s1);
    }
    if (idx < end) {
        int d0 = ebuf[idx];
        const float* h0 = h2r + (size_t)idx * HROW;
        float s0 = Pk[HID];
#pragma unroll
        for (int k = 0; k < HID; k++) s0 += h0[k] * Pk[k];
        atomicAdd(&agg[d0 * C2 + lane], s0);
    }
}

// --- K3/K7: node update + BN sums; optional out-zeroing ---
template <int CIN, int COUT>
__global__ void k_node_update(const float* __restrict__ xin, const float* __restrict__ root,
                              const float* __restrict__ bias, const float* __restrict__ agg,
                              const int* __restrict__ degi, float* __restrict__ act,
                              float* __restrict__ s1g, float* __restrict__ s2g,
                              float* zero_out) {
    __shared__ float l1[256], l2[256];
    int tid = threadIdx.x;
    if (zero_out && blockIdx.x == 0 && tid == 0) *zero_out = 0.f;
    int o = tid % COUT;
    float b = bias[o];
    float rcol[CIN];
#pragma unroll
    for (int i = 0; i < CIN; i++) rcol[i] = root[i * COUT + o];
    float acc1 = 0.f, acc2 = 0.f;
    for (int t = blockIdx.x * 256 + tid; t < N_NODES * COUT; t += NU_BLOCKS * 256) {
        int n = t / COUT;
        const float* xr = xin + (size_t)n * CIN;
        float s = b;
#pragma unroll
        for (int i = 0; i < CIN; i++) s += xr[i] * rcol[i];
        s += agg[t] / fmaxf((float)degi[n], 1.0f);
        float a = elu_f(s);
        act[t] = a;
        acc1 += a; acc2 += a * a;
    }
    l1[tid] = acc1; l2[tid] = acc2;
    __syncthreads();
    for (int s = 128; s >= COUT; s >>= 1) {
        if (tid < s) { l1[tid] += l1[tid + s]; l2[tid] += l2[tid + s]; }
        __syncthreads();
    }
    if (tid < COUT) { atomicAdd(&s1g[tid], l1[tid]); atomicAdd(&s2g[tid], l2[tid]); }
}

// --- K4: batchnorm + elu (conv1 only) ---
template <int COUT>
__global__ void k_bn_elu(const float* __restrict__ act, const float* __restrict__ s1g,
                         const float* __restrict__ s2g, const float* __restrict__ gamma,
                         const float* __restrict__ beta, float* __restrict__ out) {
    int t = blockIdx.x * blockDim.x + threadIdx.x;
    if (t >= N_NODES * COUT) return;
    int o = t % COUT;
    float m = s1g[o] * (1.0f / N_NODES);
    float v = s2g[o] * (1.0f / N_NODES) - m * m;
    float x = (act[t] - m) * rsqrtf(v + 1e-5f) * gamma[o] + beta[o];
    out[t] = elu_f(x);
}

// --- K8: BN2+elu fused + fc1 + elu + fc2 + elu + one atomicAdd per block ---
__global__ void k_fc_sum(const float* __restrict__ a2,
                         const float* __restrict__ s1g, const float* __restrict__ s2g,
                         const float* __restrict__ gamma, const float* __restrict__ beta,
                         const float* __restrict__ fc1w, const float* __restrict__ fc1b,
                         const float* __restrict__ fc2w, const float* __restrict__ fc2b,
                         float* __restrict__ out) {
    int tid = threadIdx.x;
    int lane = tid & 63;
    int wave = tid >> 6;
    float m = s1g[lane] * (1.0f / N_NODES);
    float var = s2g[lane] * (1.0f / N_NODES) - m * m;
    float scale = rsqrtf(var + 1e-5f) * gamma[lane];
    float shift = beta[lane] - m * scale;
    float b0 = fc1b[lane], b1 = fc1b[lane + 64];
    float w0 = fc2w[lane], w1 = fc2w[lane + 64];
    float fb = fc2b[0];
    float acc = 0.f;
    for (int n = blockIdx.x * 4 + wave; n < N_NODES; n += FC_BLOCKS * 4) {
        float hval = elu_f(a2[(size_t)n * C2 + lane] * scale + shift);  // coalesced
        float s0 = b0, s1 = b1;
#pragma unroll
        for (int i = 0; i < C2; i++) {
            float hv = __shfl(hval, i);
            s0 += hv * fc1w[i * 128 + lane];
            s1 += hv * fc1w[i * 128 + 64 + lane];
        }
        float v = elu_f(s0) * w0 + elu_f(s1) * w1;
#pragma unroll
        for (int off2 = 32; off2 > 0; off2 >>= 1) v += __shfl_down(v, off2);
        if (lane == 0) acc += elu_f(v + fb);
    }
    __shared__ float lds[4];
    if (lane == 0) lds[wave] = acc;
    __syncthreads();
    if (tid == 0) atomicAdd(out, lds[0] + lds[1] + lds[2] + lds[3]);
}

extern "C" void kernel_launch(void* const* d_in, const int* in_sizes, int n_in,
                              void* d_out, int out_size, void* d_ws, size_t ws_size,
                              hipStream_t stream) {
    const float* x       = (const float*)d_in[0];
    const int*   ei      = (const int*)d_in[1];
    const float* ea      = (const float*)d_in[2];
    const float* nn1_w1  = (const float*)d_in[3];
    const float* nn1_b1  = (const float*)d_in[4];
    const float* nn1_w2  = (const float*)d_in[5];
    const float* nn1_b2  = (const float*)d_in[6];
    const float* c1_root = (const float*)d_in[7];
    const float* c1_bias = (const float*)d_in[8];
    const float* bn1_g   = (const float*)d_in[9];
    const float* bn1_b   = (const float*)d_in[10];
    const float* nn2_w1  = (const float*)d_in[11];
    const float* nn2_b1  = (const float*)d_in[12];
    const float* nn2_w2  = (const float*)d_in[13];
    const float* nn2_b2  = (const float*)d_in[14];
    const float* c2_root = (const float*)d_in[15];
    const float* c2_bias = (const float*)d_in[16];
    const float* bn2_g   = (const float*)d_in[17];
    const float* bn2_b   = (const float*)d_in[18];
    const float* fc1_w   = (const float*)d_in[19];
    const float* fc1_b   = (const float*)d_in[20];
    const float* fc2_w   = (const float*)d_in[21];
    const float* fc2_b   = (const float*)d_in[22];
    float* out = (float*)d_out;

    char* ws = (char*)d_ws;
    size_t off = 0;
    auto alloc = [&](size_t nelem) -> void* {
        void* q = (void*)(ws + off);
        off += nelem * 4;
        off = (off + 255) & ~(size_t)255;
        return q;
    };
    // zeroed region first (cnt_src, cnt_dst, agg1, agg2, BN sums)
    int*   cnt_src = (int*)alloc(N_NODES);
    int*   cnt_dst = (int*)alloc(N_NODES);
    float* agg1    = (float*)alloc((size_t)N_NODES * C1);
    float* agg2    = (float*)alloc((size_t)N_NODES * C2);
    float* bn1_s1  = (float*)alloc(C1);
    float* bn1_s2  = (float*)alloc(C1);
    float* bn2_s1  = (float*)alloc(C2);
    float* bn2_s2  = (float*)alloc(C2);
    size_t zero_bytes = off;
    int*   ebuf    = (int*)alloc((size_t)N_NODES * SLOTS);
    float* h1r     = (float*)alloc((size_t)N_NODES * SLOTS * HROW);
    float* h2r     = (float*)alloc((size_t)N_NODES * SLOTS * HROW);
    float* P1      = (float*)alloc((size_t)N_NODES * (HID + 1) * C1);
    float* P2      = (float*)alloc((size_t)N_NODES * (HID + 1) * C2);
    float* a1      = (float*)alloc((size_t)N_NODES * C1);
    float* h1      = (float*)alloc((size_t)N_NODES * C1);
    float* a2      = (float*)alloc((size_t)N_NODES * C2);
    (void)ws_size; (void)in_sizes; (void)n_in; (void)out_size;

    hipMemsetAsync(d_ws, 0, zero_bytes, stream);

    constexpr int PRE1_BLOCKS = (((HID + 1) * C1 + 255) / 256) * (N_NODES / 50);  // 800
    constexpr int PRE2_BLOCKS = (((HID + 1) * C2 + 255) / 256) * (N_NODES / 50);  // 1400

    // K1: bucket scatter + edge-MLP hidden + dst degree  ||  precompute P1
    k_scatter_pre1<<<SC_BLOCKS + PRE1_BLOCKS, 256, 0, stream>>>(
        ea, ei, nn1_w1, nn1_b1, nn2_w1, nn2_b1, x, nn1_w2, nn1_b2,
        cnt_src, cnt_dst, ebuf, h1r, h2r, P1);
    // conv1
    k_msg_c1<<<(N_NODES + 3) / 4, 256, 0, stream>>>(P1, cnt_src, ebuf, h1r, agg1);
    k_node_update<FN, C1><<<NU_BLOCKS, 256, 0, stream>>>(x, c1_root, c1_bias, agg1,
                                                         cnt_dst, a1, bn1_s1, bn1_s2, nullptr);
    k_bn_elu<C1><<<(N_NODES * C1) / 256, 256, 0, stream>>>(a1, bn1_s1, bn1_s2, bn1_g, bn1_b, h1);
    // conv2
    k_precompute<C1, C2><<<PRE2_BLOCKS, 256, 0, stream>>>(h1, nn2_w2, nn2_b2, P2);
    k_msg_c2<<<(N_NODES + 3) / 4, 256, 0, stream>>>(P2, cnt_src, ebuf, h2r, agg2);
    k_node_update<C1, C2><<<NU_BLOCKS, 256, 0, stream>>>(h1, c2_root, c2_bias, agg2,
                                                         cnt_dst, a2, bn2_s1, bn2_s2, out);
    // BN2 + fc + global sum
    k_fc_sum<<<FC_BLOCKS, 256, 0, stream>>>(a2, bn2_s1, bn2_s2, bn2_g, bn2_b,
                                            fc1_w, fc1_b, fc2_w, fc2_b, out);
}

// Round 13
// 252.357 us; speedup vs baseline: 4.7328x; 1.0696x over previous
//
#include <hip/hip_runtime.h>
#include <hip/hip_bf16.h>
#include <hip/hip_fp16.h>

#define N_NODES 10000
#define N_EDGES 80000
#define FN 16
#define FE 8
#define HID 25
#define C1 32
#define C2 64
#define NU_BLOCKS 256
#define FC_BLOCKS 640
#define HROW 28   // padded h row in halfs (25 used; 56B rows, 8B-aligned)
#define SLOTS 40  // bucket capacity; Poisson(8) => P(deg>=40) ~ 5e-16
#define SC_BLOCKS ((N_EDGES + 255) / 256)  // 313

typedef _Float16 h16;

__device__ __forceinline__ float elu_f(float x) { return x > 0.f ? x : (expf(x) - 1.f); }

// --- m-major precompute (fp16 out): P[n,k*COUT+o] = sum_i x[n,i]*w2[k,i,o];
//     row k==HID is the b2 term. One w2 column per thread, reused for 50 nodes. ---
template <int CIN, int COUT>
__device__ __forceinline__ void pre_block(const float* __restrict__ xin,
                                          const float* __restrict__ w2,
                                          const float* __restrict__ b2,
                                          h16* __restrict__ P, int u, int tid) {
    constexpr int M = (HID + 1) * COUT;
    constexpr int MB = (M + 255) / 256;
    constexpr int TN = 50;
    int mb = u % MB;
    int n0 = (u / MB) * TN;
    int m = mb * 256 + tid;
    if (m >= M) return;
    int k = m / COUT, o = m % COUT;
    float wreg[CIN];
    if (k < HID) {
#pragma unroll
        for (int i = 0; i < CIN; i++) wreg[i] = w2[(size_t)(k * CIN + i) * COUT + o];
    } else {
#pragma unroll
        for (int i = 0; i < CIN; i++) wreg[i] = b2[i * COUT + o];
    }
    for (int n = n0; n < n0 + TN; n++) {
        const float* xr = xin + (size_t)n * CIN;  // wave-uniform -> s_load
        float s = 0.f;
#pragma unroll
        for (int i = 0; i < CIN; i++) s += xr[i] * wreg[i];
        P[(size_t)n * M + m] = (h16)s;
    }
}

// --- K1: blocks [0,SC_BLOCKS): bucket-scatter + edge-MLP hidden (fp16 rows) +
//         dst degree. blocks beyond: m-major precompute of P1. ---
__global__ void k_scatter_pre1(const float* __restrict__ ea, const int* __restrict__ ei,
                               const float* __restrict__ w1a, const float* __restrict__ b1a,
                               const float* __restrict__ w1b, const float* __restrict__ b1b,
                               const float* __restrict__ x, const float* __restrict__ w2a,
                               const float* __restrict__ b2a,
                               int* __restrict__ cnt_src, int* __restrict__ cnt_dst,
                               int* __restrict__ ebuf, h16* __restrict__ h1r,
                               h16* __restrict__ h2r, h16* __restrict__ P1) {
    int tid = threadIdx.x;
    int bid = blockIdx.x;
    if (bid >= SC_BLOCKS) {
        pre_block<FN, C1>(x, w2a, b2a, P1, bid - SC_BLOCKS, tid);
        return;
    }
    __shared__ float sw1a[FE * HID], sw1b[FE * HID], sb1a[HID], sb1b[HID];
    for (int i = tid; i < FE * HID; i += 256) { sw1a[i] = w1a[i]; sw1b[i] = w1b[i]; }
    if (tid < HID) { sb1a[tid] = b1a[tid]; sb1b[tid] = b1b[tid]; }
    __syncthreads();
    int e = bid * 256 + tid;
    if (e >= N_EDGES) return;
    float a[FE];
#pragma unroll
    for (int i = 0; i < FE; i++) a[i] = ea[e * FE + i];
    int src = ei[e], dst = ei[N_EDGES + e];
    int slot = atomicAdd(&cnt_src[src], 1);
    int pos = src * SLOTS + slot;
    ebuf[pos] = dst;
    atomicAdd(&cnt_dst[dst], 1);
    h16* h1p = h1r + (size_t)pos * HROW;
    h16* h2p = h2r + (size_t)pos * HROW;
#pragma unroll
    for (int k = 0; k < HID; k++) {
        float s1 = sb1a[k], s2 = sb1b[k];
#pragma unroll
        for (int i = 0; i < FE; i++) { s1 += a[i] * sw1a[i * HID + k]; s2 += a[i] * sw1b[i * HID + k]; }
        h1p[k] = (h16)fmaxf(s1, 0.f);
        h2p[k] = (h16)fmaxf(s2, 0.f);
    }
}

// --- K5: conv2 precompute (standalone) ---
template <int CIN, int COUT>
__global__ void k_precompute(const float* __restrict__ xin, const float* __restrict__ w2,
                             const float* __restrict__ b2, h16* __restrict__ P) {
    pre_block<CIN, COUT>(xin, w2, b2, P, blockIdx.x, threadIdx.x);
}

// --- K2: conv1 message. Wave per node; paired edges in half-waves; node index
//         scalarized -> bucket/h-row loads become s_load. ---
__global__ void k_msg_c1(const h16* __restrict__ P, const int* __restrict__ cnt_src,
                         const int* __restrict__ ebuf, const h16* __restrict__ h1r,
                         float* __restrict__ agg) {
    constexpr int M = (HID + 1) * C1;
    int lane = threadIdx.x & 63;
    int o = lane & 31;
    int n = __builtin_amdgcn_readfirstlane(blockIdx.x * 4 + (threadIdx.x >> 6));
    if (n >= N_NODES) return;
    const h16* Pr = P + (size_t)n * M;
    float Pk[HID + 1];
#pragma unroll
    for (int k = 0; k <= HID; k++) Pk[k] = (float)Pr[k * C1 + o];
    int beg = n * SLOTS, end = beg + cnt_src[n];
    int idx = beg;
    for (; idx + 1 < end; idx += 2) {
        int d0 = ebuf[idx], d1 = ebuf[idx + 1];
        const h16* h0 = h1r + (size_t)idx * HROW;
        const h16* h1 = h1r + (size_t)(idx + 1) * HROW;
        float s0 = Pk[HID], s1 = Pk[HID];
#pragma unroll
        for (int k = 0; k < HID; k++) { s0 += (float)h0[k] * Pk[k]; s1 += (float)h1[k] * Pk[k]; }
        float val = (lane < 32) ? s0 : s1;
        int dsel = (lane < 32) ? d0 : d1;
        atomicAdd(&agg[dsel * C1 + o], val);
    }
    if (idx < end) {
        int d0 = ebuf[idx];
        const h16* h0 = h1r + (size_t)idx * HROW;
        float s0 = Pk[HID];
#pragma unroll
        for (int k = 0; k < HID; k++) s0 += (float)h0[k] * Pk[k];
        if (lane < 32) atomicAdd(&agg[d0 * C1 + o], s0);
    }
}

// --- K6: conv2 message. Wave per node; lane = channel; 2-edge unroll. ---
__global__ void k_msg_c2(const h16* __restrict__ P, const int* __restrict__ cnt_src,
                         const int* __restrict__ ebuf, const h16* __restrict__ h2r,
                         float* __restrict__ agg) {
    constexpr int M = (HID + 1) * C2;
    int lane = threadIdx.x & 63;
    int n = __builtin_amdgcn_readfirstlane(blockIdx.x * 4 + (threadIdx.x >> 6));
    if (n >= N_NODES) return;
    const h16* Pr = P + (size_t)n * M;
    float Pk[HID + 1];
#pragma unroll
    for (int k = 0; k <= HID; k++) Pk[k] = (float)Pr[k * C2 + lane];
    int beg = n * SLOTS, end = beg + cnt_src[n];
    int idx = beg;
    for (; idx + 1 < end; idx += 2) {
        int d0 = ebuf[idx], d1 = ebuf[idx + 1];
        const h16* h0 = h2r + (size_t)idx * HROW;
        const h16* h1 = h2r + (size_t)(idx + 1) * HROW;
        float s0 = Pk[HID], s1 = Pk[HID];
#pragma unroll
        for (int k = 0; k < HID; k++) { s0 += (float)h0[k] * Pk[k]; s1 += (float)h1[k] * Pk[k]; }
        atomicAdd(&agg[d0 * C2 + lane], s0);
        atomicAdd(&agg[d1 * C2 + lane], s1);
    }
    if (idx < end) {
        int d0 = ebuf[idx];
        const h16* h0 = h2r + (size_t)idx * HROW;
        float s0 = Pk[HID];
#pragma unroll
        for (int k = 0; k < HID; k++) s0 += (float)h0[k] * Pk[k];
        atomicAdd(&agg[d0 * C2 + lane], s0);
    }
}

// --- K3/K7: node update + BN sums; optional out-zeroing ---
template <int CIN, int COUT>
__global__ void k_node_update(const float* __restrict__ xin, const float* __restrict__ root,
                              const float* __restrict__ bias, const float* __restrict__ agg,
                              const int* __restrict__ degi, float* __restrict__ act,
                              float* __restrict__ s1g, float* __restrict__ s2g,
                              float* zero_out) {
    __shared__ float l1[256], l2[256];
    int tid = threadIdx.x;
    if (zero_out && blockIdx.x == 0 && tid == 0) *zero_out = 0.f;
    int o = tid % COUT;
    float b = bias[o];
    float rcol[CIN];
#pragma unroll
    for (int i = 0; i < CIN; i++) rcol[i] = root[i * COUT + o];
    float acc1 = 0.f, acc2 = 0.f;
    for (int t = blockIdx.x * 256 + tid; t < N_NODES * COUT; t += NU_BLOCKS * 256) {
        int n = t / COUT;
        const float* xr = xin + (size_t)n * CIN;
        float s = b;
#pragma unroll
        for (int i = 0; i < CIN; i++) s += xr[i] * rcol[i];
        s += agg[t] / fmaxf((float)degi[n], 1.0f);
        float a = elu_f(s);
        act[t] = a;
        acc1 += a; acc2 += a * a;
    }
    l1[tid] = acc1; l2[tid] = acc2;
    __syncthreads();
    for (int s = 128; s >= COUT; s >>= 1) {
        if (tid < s) { l1[tid] += l1[tid + s]; l2[tid] += l2[tid + s]; }
        __syncthreads();
    }
    if (tid < COUT) { atomicAdd(&s1g[tid], l1[tid]); atomicAdd(&s2g[tid], l2[tid]); }
}

// --- K4: batchnorm + elu (conv1 only) ---
template <int COUT>
__global__ void k_bn_elu(const float* __restrict__ act, const float* __restrict__ s1g,
                         const float* __restrict__ s2g, const float* __restrict__ gamma,
                         const float* __restrict__ beta, float* __restrict__ out) {
    int t = blockIdx.x * blockDim.x + threadIdx.x;
    if (t >= N_NODES * COUT) return;
    int o = t % COUT;
    float m = s1g[o] * (1.0f / N_NODES);
    float v = s2g[o] * (1.0f / N_NODES) - m * m;
    float x = (act[t] - m) * rsqrtf(v + 1e-5f) * gamma[o] + beta[o];
    out[t] = elu_f(x);
}

// --- K8: BN2+elu fused + fc1 + elu + fc2 + elu + one atomicAdd per block ---
__global__ void k_fc_sum(const float* __restrict__ a2,
                         const float* __restrict__ s1g, const float* __restrict__ s2g,
                         const float* __restrict__ gamma, const float* __restrict__ beta,
                         const float* __restrict__ fc1w, const float* __restrict__ fc1b,
                         const float* __restrict__ fc2w, const float* __restrict__ fc2b,
                         float* __restrict__ out) {
    int tid = threadIdx.x;
    int lane = tid & 63;
    int wave = tid >> 6;
    float m = s1g[lane] * (1.0f / N_NODES);
    float var = s2g[lane] * (1.0f / N_NODES) - m * m;
    float scale = rsqrtf(var + 1e-5f) * gamma[lane];
    float shift = beta[lane] - m * scale;
    float b0 = fc1b[lane], b1 = fc1b[lane + 64];
    float w0 = fc2w[lane], w1 = fc2w[lane + 64];
    float fb = fc2b[0];
    float acc = 0.f;
    for (int n = blockIdx.x * 4 + wave; n < N_NODES; n += FC_BLOCKS * 4) {
        float hval = elu_f(a2[(size_t)n * C2 + lane] * scale + shift);  // coalesced
        float s0 = b0, s1 = b1;
#pragma unroll
        for (int i = 0; i < C2; i++) {
            float hv = __shfl(hval, i);
            s0 += hv * fc1w[i * 128 + lane];
            s1 += hv * fc1w[i * 128 + 64 + lane];
        }
        float v = elu_f(s0) * w0 + elu_f(s1) * w1;
#pragma unroll
        for (int off2 = 32; off2 > 0; off2 >>= 1) v += __shfl_down(v, off2);
        if (lane == 0) acc += elu_f(v + fb);
    }
    __shared__ float lds[4];
    if (lane == 0) lds[wave] = acc;
    __syncthreads();
    if (tid == 0) atomicAdd(out, lds[0] + lds[1] + lds[2] + lds[3]);
}

extern "C" void kernel_launch(void* const* d_in, const int* in_sizes, int n_in,
                              void* d_out, int out_size, void* d_ws, size_t ws_size,
                              hipStream_t stream) {
    const float* x       = (const float*)d_in[0];
    const int*   ei      = (const int*)d_in[1];
    const float* ea      = (const float*)d_in[2];
    const float* nn1_w1  = (const float*)d_in[3];
    const float* nn1_b1  = (const float*)d_in[4];
    const float* nn1_w2  = (const float*)d_in[5];
    const float* nn1_b2  = (const float*)d_in[6];
    const float* c1_root = (const float*)d_in[7];
    const float* c1_bias = (const float*)d_in[8];
    const float* bn1_g   = (const float*)d_in[9];
    const float* bn1_b   = (const float*)d_in[10];
    const float* nn2_w1  = (const float*)d_in[11];
    const float* nn2_b1  = (const float*)d_in[12];
    const float* nn2_w2  = (const float*)d_in[13];
    const float* nn2_b2  = (const float*)d_in[14];
    const float* c2_root = (const float*)d_in[15];
    const float* c2_bias = (const float*)d_in[16];
    const float* bn2_g   = (const float*)d_in[17];
    const float* bn2_b   = (const float*)d_in[18];
    const float* fc1_w   = (const float*)d_in[19];
    const float* fc1_b   = (const float*)d_in[20];
    const float* fc2_w   = (const float*)d_in[21];
    const float* fc2_b   = (const float*)d_in[22];
    float* out = (float*)d_out;

    char* ws = (char*)d_ws;
    size_t off = 0;
    auto alloc = [&](size_t nbytes) -> void* {
        void* q = (void*)(ws + off);
        off += nbytes;
        off = (off + 255) & ~(size_t)255;
        return q;
    };
    // zeroed region first (cnt_src, cnt_dst, agg1, agg2, BN sums)
    int*   cnt_src = (int*)alloc(N_NODES * 4);
    int*   cnt_dst = (int*)alloc(N_NODES * 4);
    float* agg1    = (float*)alloc((size_t)N_NODES * C1 * 4);
    float* agg2    = (float*)alloc((size_t)N_NODES * C2 * 4);
    float* bn1_s1  = (float*)alloc(C1 * 4);
    float* bn1_s2  = (float*)alloc(C1 * 4);
    float* bn2_s1  = (float*)alloc(C2 * 4);
    float* bn2_s2  = (float*)alloc(C2 * 4);
    size_t zero_bytes = off;
    int*   ebuf    = (int*)alloc((size_t)N_NODES * SLOTS * 4);
    h16*   h1r     = (h16*)alloc((size_t)N_NODES * SLOTS * HROW * 2);
    h16*   h2r     = (h16*)alloc((size_t)N_NODES * SLOTS * HROW * 2);
    h16*   P1      = (h16*)alloc((size_t)N_NODES * (HID + 1) * C1 * 2);
    h16*   P2      = (h16*)alloc((size_t)N_NODES * (HID + 1) * C2 * 2);
    float* a1      = (float*)alloc((size_t)N_NODES * C1 * 4);
    float* h1      = (float*)alloc((size_t)N_NODES * C1 * 4);
    float* a2      = (float*)alloc((size_t)N_NODES * C2 * 4);
    (void)ws_size; (void)in_sizes; (void)n_in; (void)out_size;

    hipMemsetAsync(d_ws, 0, zero_bytes, stream);

    constexpr int PRE1_BLOCKS = (((HID + 1) * C1 + 255) / 256) * (N_NODES / 50);  // 800
    constexpr int PRE2_BLOCKS = (((HID + 1) * C2 + 255) / 256) * (N_NODES / 50);  // 1400

    // K1: bucket scatter + edge-MLP hidden + dst degree  ||  precompute P1
    k_scatter_pre1<<<SC_BLOCKS + PRE1_BLOCKS, 256, 0, stream>>>(
        ea, ei, nn1_w1, nn1_b1, nn2_w1, nn2_b1, x, nn1_w2, nn1_b2,
        cnt_src, cnt_dst, ebuf, h1r, h2r, P1);
    // conv1
    k_msg_c1<<<(N_NODES + 3) / 4, 256, 0, stream>>>(P1, cnt_src, ebuf, h1r, agg1);
    k_node_update<FN, C1><<<NU_BLOCKS, 256, 0, stream>>>(x, c1_root, c1_bias, agg1,
                                                         cnt_dst, a1, bn1_s1, bn1_s2, nullptr);
    k_bn_elu<C1><<<(N_NODES * C1) / 256, 256, 0, stream>>>(a1, bn1_s1, bn1_s2, bn1_g, bn1_b, h1);
    // conv2
    k_precompute<C1, C2><<<PRE2_BLOCKS, 256, 0, stream>>>(h1, nn2_w2, nn2_b2, P2);
    k_msg_c2<<<(N_NODES + 3) / 4, 256, 0, stream>>>(P2, cnt_src, ebuf, h2r, agg2);
    k_node_update<C1, C2><<<NU_BLOCKS, 256, 0, stream>>>(h1, c2_root, c2_bias, agg2,
                                                         cnt_dst, a2, bn2_s1, bn2_s2, out);
    // BN2 + fc + global sum
    k_fc_sum<<<FC_BLOCKS, 256, 0, stream>>>(a2, bn2_s1, bn2_s2, bn2_g, bn2_b,
                                            fc1_w, fc1_b, fc2_w, fc2_b, out);
}